// Round 7
// baseline (376.375 us; speedup 1.0000x reference)
//
#include <hip/hip_runtime.h>
#include <math.h>

// ---------------------------------------------------------------------------
// out = (silu(x) @ (W/sigma)^T + b  +  softthr(basis(x) @ Ww^T)) * oscale
// Merged K = [kan 7168 | base 1024] = 8192, bf16 MFMA (32x32x16).
// BM=256 x BN=128, BK=64, 8 waves (4M x 2N, 64x64 wave tiles, 2x2 of 32x32).
// FAT-PHASE schedule: 3 LDS buffers, stage t+2, ONE barrier per K-tile,
// counted lgkmcnt(8)/vmcnt(6). softthr in-register at tile 112.
// ---------------------------------------------------------------------------

typedef __attribute__((ext_vector_type(4)))  float  f32x4;
typedef __attribute__((ext_vector_type(16))) float  f32x16;
typedef __attribute__((ext_vector_type(8)))  __bf16 bf16x8;
typedef __attribute__((ext_vector_type(8)))  unsigned short u16x8;

#define NROWS 16384
#define INF   1024
#define OUTF  1024
#define GG    7
#define KKAN  7168
#define KTOT  8192

static __device__ __forceinline__ unsigned short f2bf(float f) {
  union { float f; unsigned int u; } v; v.f = f;
  unsigned int r = v.u + 0x7fffu + ((v.u >> 16) & 1u);  // RNE
  return (unsigned short)(r >> 16);
}

// ---------------- sigma (spectral norm) ----------------
__global__ void zero_t(float* __restrict__ t) { t[threadIdx.x] = 0.f; }

// t = W^T u, coalesced: 64 blocks x 16 rows, reg accumulate, 1 atomic pass
__global__ void wtu_acc(const float* __restrict__ W, const float* __restrict__ u,
                        float* __restrict__ t) {
  int tid = threadIdx.x;            // 256
  int j4 = tid * 4;
  int i0 = blockIdx.x * 16;
  f32x4 acc = {0.f, 0.f, 0.f, 0.f};
  for (int i = i0; i < i0 + 16; ++i) {
    float ui = u[i];
    f32x4 w4 = *(const f32x4*)(W + (size_t)i * INF + j4);
    acc[0] += w4[0] * ui; acc[1] += w4[1] * ui;
    acc[2] += w4[2] * ui; acc[3] += w4[3] * ui;
  }
  atomicAdd(&t[j4 + 0], acc[0]);
  atomicAdd(&t[j4 + 1], acc[1]);
  atomicAdd(&t[j4 + 2], acc[2]);
  atomicAdd(&t[j4 + 3], acc[3]);
}

__global__ void mv_w_t(const float* __restrict__ W, const float* __restrict__ t,
                       float* __restrict__ s) {
  int i = blockIdx.x;
  int tid = threadIdx.x;
  float p = 0.f;
  for (int j = tid; j < INF; j += 256) p += W[(size_t)i * INF + j] * t[j];
  __shared__ float red[256];
  red[tid] = p; __syncthreads();
  for (int k = 128; k > 0; k >>= 1) { if (tid < k) red[tid] += red[tid + k]; __syncthreads(); }
  if (tid == 0) s[i] = red[0];
}

__global__ void sigma_finish(const float* __restrict__ t, const float* __restrict__ s,
                             const float* __restrict__ st, const float* __restrict__ os,
                             float* __restrict__ scal) {
  __shared__ float r1[256], r2[256];
  int tid = threadIdx.x;
  float p1 = 0.f, p2 = 0.f;
  for (int i = tid; i < 1024; i += 256) { float a = t[i]; p1 += a * a; float b = s[i]; p2 += b * b; }
  r1[tid] = p1; r2[tid] = p2; __syncthreads();
  for (int k = 128; k > 0; k >>= 1) { if (tid < k) { r1[tid] += r1[tid + k]; r2[tid] += r2[tid + k]; } __syncthreads(); }
  if (tid == 0) {
    float nt = sqrtf(r1[0]);
    float ns = sqrtf(r2[0]);
    float nq = ns / (nt + 1e-12f);
    float sigma = nq * nq / (nq + 1e-12f);
    scal[0] = 1.f / sigma;
    scal[1] = log1pf(__expf(st[0]));
    scal[2] = os[0];
  }
}

// ---------------- weight casts into W' [1024][8192] ----------------
__global__ void wsn_cast(const float* __restrict__ w, const float* __restrict__ scal,
                         unsigned short* __restrict__ Wp) {
  float is = scal[0];
  int idx = blockIdx.x * 256 + threadIdx.x;
  int row = idx >> 7, i0 = (idx & 127) << 3;
  const f32x4* p = (const f32x4*)(w + (size_t)row * INF + i0);
  f32x4 a = p[0], b = p[1];
  u16x8 v;
  v[0] = f2bf(a[0] * is); v[1] = f2bf(a[1] * is); v[2] = f2bf(a[2] * is); v[3] = f2bf(a[3] * is);
  v[4] = f2bf(b[0] * is); v[5] = f2bf(b[1] * is); v[6] = f2bf(b[2] * is); v[7] = f2bf(b[3] * is);
  *(u16x8*)(Wp + (size_t)row * KTOT + KKAN + i0) = v;
}

__global__ void wkan_cast(const float* __restrict__ w, unsigned short* __restrict__ Wp) {
  __shared__ float row[KKAN];
  int orow = blockIdx.x;
  const float* src = w + (size_t)orow * KKAN;
  for (int c = threadIdx.x * 4; c < KKAN; c += 1024)
    *(f32x4*)&row[c] = *(const f32x4*)&src[c];
  __syncthreads();
  unsigned short* dst = Wp + (size_t)orow * KTOT;
  for (int r = threadIdx.x; r < 896; r += 256) {
    int g = r >> 7, i0 = (r & 127) << 3;
    u16x8 v;
#pragma unroll
    for (int j = 0; j < 8; j++) v[j] = f2bf(row[(i0 + j) * GG + g]);
    *(u16x8*)(dst + g * 1024 + i0) = v;
  }
}

// ---------------- activation expansion into A' [rows][8192] ----------------
__global__ void expand_kernel(const float* __restrict__ x,
                              const float* __restrict__ translation,
                              const float* __restrict__ scale,
                              unsigned short* __restrict__ Ap,
                              int row0, int nrows) {
  float tr[GG], iss[GG];
#pragma unroll
  for (int g = 0; g < GG; g++) {
    tr[g] = translation[g];
    float s = fabsf(scale[g]);
    iss[g] = 1.f / (s < 0.1f ? 0.1f : s);
  }
  int units = nrows * (INF / 8);
  int stride = gridDim.x * blockDim.x;
  for (int uu = blockIdx.x * blockDim.x + threadIdx.x; uu < units; uu += stride) {
    int nloc = uu >> 7;
    int i0 = (uu & 127) << 3;
    const f32x4* xp = (const f32x4*)(x + (size_t)(row0 + nloc) * INF + i0);
    f32x4 xa = xp[0], xb = xp[1];
    float xv[8] = {xa[0], xa[1], xa[2], xa[3], xb[0], xb[1], xb[2], xb[3]};
    u16x8 sb, kb[GG];
#pragma unroll
    for (int j = 0; j < 8; j++) {
      float xx = xv[j];
      float si = xx / (1.f + __expf(-xx));
      sb[j] = f2bf(si);
      float e2 = __expf(2.f * xx);
      float xn = 2.5f * (1.f - 2.f / (e2 + 1.f));
#pragma unroll
      for (int g = 0; g < GG; g++) {
        float xe = (xn - tr[g]) * iss[g];
        float t2 = xe * xe;
        float b = (1.f - t2) * __expf(-0.5f * t2);
        kb[g][j] = f2bf(b);
      }
    }
    unsigned short* rp = Ap + (size_t)nloc * KTOT;
    *(u16x8*)(rp + KKAN + i0) = sb;
#pragma unroll
    for (int g = 0; g < GG; g++) *(u16x8*)(rp + g * 1024 + i0) = kb[g];
  }
}

// ---------------- GEMM machinery ----------------
static __device__ __forceinline__ void gload16(const unsigned short* g, unsigned short* l) {
  __builtin_amdgcn_global_load_lds(
      (const __attribute__((address_space(1))) unsigned int*)g,
      (__attribute__((address_space(3))) unsigned int*)l, 16, 0, 0);
}

#define SCB   __builtin_amdgcn_sched_barrier(0)
#define SBAR  do { SCB; __builtin_amdgcn_s_barrier(); } while (0)
#define VM(N) asm volatile("s_waitcnt vmcnt(" #N ")" ::: "memory")
#define LG(N) asm volatile("s_waitcnt lgkmcnt(" #N ")" ::: "memory")

// stage full K-tile tt into buffer db: A 256x64 (4 gloads) + B 128x64 (2)
#define STAGE(db, tt) do { \
    const unsigned short* _sa = gA + (size_t)(tt) * 64; \
    const unsigned short* _sb = gB + (size_t)(tt) * 64; \
    unsigned short* _da = ldsS + (db) * 24576; \
    unsigned short* _db = ldsS + (db) * 24576 + 16384; \
    gload16(_sa,                       _da); \
    gload16(_sa + (size_t)64  * KTOT,  _da + 4096); \
    gload16(_sa + (size_t)128 * KTOT,  _da + 8192); \
    gload16(_sa + (size_t)192 * KTOT,  _da + 12288); \
    gload16(_sb,                       _db); \
    gload16(_sb + (size_t)64  * KTOT,  _db + 4096); \
  } while (0)

// one k-step's 4 frags: a0,a1 (rows +0..31,+32..63), b0,b1 (cols +0..31,+32..63)
#define RD4(dst, bb, kx) do { \
    dst[0] = *(const bf16x8*)(pA + (bb) * 49152 + (kx)); \
    dst[1] = *(const bf16x8*)(pA + (bb) * 49152 + 4096 + (kx)); \
    dst[2] = *(const bf16x8*)(pB + (bb) * 49152 + (kx)); \
    dst[3] = *(const bf16x8*)(pB + (bb) * 49152 + 4096 + (kx)); \
  } while (0)

#define MM4(F) do { \
    acc[0][0] = __builtin_amdgcn_mfma_f32_32x32x16_bf16(F[0], F[2], acc[0][0], 0, 0, 0); \
    acc[0][1] = __builtin_amdgcn_mfma_f32_32x32x16_bf16(F[0], F[3], acc[0][1], 0, 0, 0); \
    acc[1][0] = __builtin_amdgcn_mfma_f32_32x32x16_bf16(F[1], F[2], acc[1][0], 0, 0, 0); \
    acc[1][1] = __builtin_amdgcn_mfma_f32_32x32x16_bf16(F[1], F[3], acc[1][1], 0, 0, 0); \
  } while (0)

// one K-tile: 16 reads + stage(t+2) + 2 fat MFMA groups + 1 barrier
#define TILE(tt, bb, db, SS, WAIT) do { \
    RD4(g0a, bb, kx0); RD4(g0b, bb, kx1); \
    SCB; \
    RD4(g1a, bb, kx2); RD4(g1b, bb, kx3); \
    SCB; \
    if (SS) STAGE(db, (tt) + 2); \
    SCB; \
    LG(8); SCB; \
    __builtin_amdgcn_s_setprio(1); MM4(g0a); MM4(g0b); __builtin_amdgcn_s_setprio(0); \
    LG(0); SCB; \
    __builtin_amdgcn_s_setprio(1); MM4(g1a); MM4(g1b); __builtin_amdgcn_s_setprio(0); \
    WAIT; \
    SBAR; \
  } while (0)

// BM=256 x BN=128, 8 waves (4M x 2N), K = 8192 merged, softthr at tile 112
__global__ __launch_bounds__(512, 2) void gemm_k(
    const unsigned short* __restrict__ A,   // [mt*256][8192] bf16
    const unsigned short* __restrict__ W,   // [1024][8192] bf16
    const float* __restrict__ bias,
    const float* __restrict__ scal,
    float* __restrict__ out) {              // [mt*256][1024]
  __shared__ unsigned short lds[73728];     // 3 buffers x 48 KB (A 32K | B 16K)

  int bid = blockIdx.x;
  int cpx = gridDim.x >> 3;                 // grid % 8 == 0 (mt*8)
  int swz = (bid & 7) * cpx + (bid >> 3);   // XCD-bijective; n-inner => A reuse
  int m0 = (swz >> 3) * 256;
  int n0 = (swz & 7) * 128;
  int tid = threadIdx.x;
  int wv = tid >> 6, l = tid & 63;
  int wr = wv >> 1, wc = wv & 1;            // 4M x 2N waves, 64x64 tiles

  float thr = scal[1], osc = scal[2];

  // staging: thread covers row (tid>>3) (+64/round), XOR-preswizzled 16B chunk
  int rowq = tid >> 3;
  int swk = ((tid & 7) ^ (rowq & 7)) << 3;
  const unsigned short* gA = A + (size_t)(m0 + rowq) * KTOT + swk;
  const unsigned short* gB = W + (size_t)(n0 + rowq) * KTOT + swk;
  unsigned short* ldsS = lds + wv * 512;    // wave-uniform dest base

  // frag reads: lane l holds row base+(l&31), k-group hi=l>>5 (8 bf16, 16 B)
  int l31 = l & 31;
  int hi  = l >> 5;
  int r7x = (l & 7) << 4;                   // XOR read-side swizzle
  int kx0 = (((0 * 2 + hi) << 4) ^ r7x);
  int kx1 = (((1 * 2 + hi) << 4) ^ r7x);
  int kx2 = (((2 * 2 + hi) << 4) ^ r7x);
  int kx3 = (((3 * 2 + hi) << 4) ^ r7x);
  const char* pA = (const char*)lds + (wr * 64 + l31) * 128;
  const char* pB = (const char*)lds + 32768 + (wc * 64 + l31) * 128;

  bf16x8 g0a[4], g0b[4], g1a[4], g1b[4];
  f32x16 acc[2][2] = {};

  // prologue: stage tiles 0,1 into buf 0,1; wait tile 0 landed (6 outstanding)
  STAGE(0, 0);
  STAGE(1, 1);
  VM(6);
  SBAR;

  // kan segment: tiles 0..111
  for (int t = 0; t < 108; t += 3) {
    TILE(t,     0, 2, 1, VM(6));
    TILE(t + 1, 1, 0, 1, VM(6));
    TILE(t + 2, 2, 1, 1, VM(6));
  }
  TILE(108, 0, 2, 1, VM(6));
  TILE(109, 1, 0, 1, VM(6));
  TILE(110, 2, 1, 1, VM(6));
  TILE(111, 0, 2, 1, VM(6));

  // soft-threshold in-register at the kan/base boundary
#pragma unroll
  for (int i = 0; i < 2; ++i)
#pragma unroll
    for (int j = 0; j < 2; ++j)
#pragma unroll
      for (int e = 0; e < 16; ++e) {
        float v = acc[i][j][e];
        float a = fabsf(v) - thr;
        a = a > 0.f ? a : 0.f;
        acc[i][j][e] = v > 0.f ? a : -a;
      }

  // base segment: tiles 112..127
  for (int t = 112; t < 124; t += 3) {
    TILE(t,     1, 0, 1, VM(6));
    TILE(t + 1, 2, 1, 1, VM(6));
    TILE(t + 2, 0, 2, 1, VM(6));
  }
  TILE(124, 1, 0, 1, VM(6));
  TILE(125, 2, 1, 1, VM(6));
  TILE(126, 0, 2, 0, VM(0));
  TILE(127, 1, 2, 0, (void)0);

  // epilogue: out = (acc + bias) * oscale
  // D layout (32x32): col = l&31, row = (e&3) + 8*(e>>2) + 4*hi
  int rr = m0 + wr * 64 + 4 * hi;
  int cc = n0 + wc * 64 + l31;
#pragma unroll
  for (int i = 0; i < 2; ++i)
#pragma unroll
    for (int j = 0; j < 2; ++j) {
      int c = cc + j * 32;
      float bc = bias[c];
#pragma unroll
      for (int e = 0; e < 16; ++e) {
        int r = rr + i * 32 + (e & 3) + 8 * (e >> 2);
        out[(size_t)r * OUTF + c] = (acc[i][j][e] + bc) * osc;
      }
    }
}

// ---------------------------------------------------------------------------
extern "C" void kernel_launch(void* const* d_in, const int* in_sizes, int n_in,
                              void* d_out, int out_size, void* d_ws, size_t ws_size,
                              hipStream_t stream) {
  const float* x              = (const float*)d_in[0];
  const float* base_w         = (const float*)d_in[1];
  const float* base_b         = (const float*)d_in[2];
  const float* u              = (const float*)d_in[3];
  const float* translation    = (const float*)d_in[4];
  const float* scale          = (const float*)d_in[5];
  const float* wavelet_w      = (const float*)d_in[6];
  const float* soft_threshold = (const float*)d_in[7];
  const float* output_scale   = (const float*)d_in[8];
  float* out = (float*)d_out;

  char* ws = (char*)d_ws;
  float* t_vec = (float*)ws;
  float* s_vec = t_vec + 1024;
  float* scal  = s_vec + 1024;
  unsigned short* Wp = (unsigned short*)(ws + 16384);    // 16 MB
  char* dynbuf = ws + 16384 + (size_t)KTOT * OUTF * 2;

  size_t fixed = 16384 + (size_t)KTOT * OUTF * 2;
  size_t avail = ws_size > fixed ? ws_size - fixed : 0;

  zero_t<<<1, 1024, 0, stream>>>(t_vec);
  wtu_acc<<<64, 256, 0, stream>>>(base_w, u, t_vec);
  mv_w_t<<<1024, 256, 0, stream>>>(base_w, t_vec, s_vec);
  sigma_finish<<<1, 256, 0, stream>>>(t_vec, s_vec, soft_threshold, output_scale, scal);
  wsn_cast<<<512, 256, 0, stream>>>(base_w, scal, Wp);
  wkan_cast<<<1024, 256, 0, stream>>>(wavelet_w, Wp);

  const size_t ROW = (size_t)KTOT * 2;      // A' bytes per row
  size_t total = (size_t)NROWS * ROW;
  int nch = (int)((total + (avail > 0 ? avail : 1) - 1) / (avail > 0 ? avail : 1));
  if (nch < 1) nch = 1;
  long mc = (((NROWS + nch - 1) / nch) + 255) & ~255L;
  while (mc > 256 && (size_t)mc * ROW > avail) mc -= 256;
  if (mc < 256) mc = 256;   // assume ws >= ~21 MB

  unsigned short* Ap = (unsigned short*)dynbuf;

  for (long r0 = 0; r0 < NROWS; r0 += mc) {
    long nr = (NROWS - r0 < mc) ? (NROWS - r0) : mc;
    expand_kernel<<<2048, 256, 0, stream>>>(x, translation, scale, Ap, (int)r0, (int)nr);
    int mt = (int)(nr / 256);
    gemm_k<<<mt * 8, 512, 0, stream>>>(Ap, Wp, base_b, scal, out + (size_t)r0 * OUTF);
  }
}

// Round 8
// 334.126 us; speedup vs baseline: 1.1264x; 1.1264x over previous
//
#include <hip/hip_runtime.h>
#include <math.h>

// ---------------------------------------------------------------------------
// out = (silu(x) @ (W/sigma)^T + b  +  softthr(basis(x) @ Ww^T)) * oscale
// Merged K = [kan 7168 | base 1024] = 8192, bf16 MFMA (16x16x32).
// BM=256 x BN=128, BK=64, 8 waves (4M x 2N, 64x64 wave tiles).
// Software-pipelined frags: 3 LDS buffers, stage t+2, read half-K one phase
// ahead into alternate register set; ONE barrier + counted vmcnt(6) per tile.
// softthr in-register at tile 112.
// ---------------------------------------------------------------------------

typedef __attribute__((ext_vector_type(4))) float  f32x4;
typedef __attribute__((ext_vector_type(8))) __bf16 bf16x8;
typedef __attribute__((ext_vector_type(8))) unsigned short u16x8;

#define NROWS 16384
#define INF   1024
#define OUTF  1024
#define GG    7
#define KKAN  7168
#define KTOT  8192

static __device__ __forceinline__ unsigned short f2bf(float f) {
  union { float f; unsigned int u; } v; v.f = f;
  unsigned int r = v.u + 0x7fffu + ((v.u >> 16) & 1u);  // RNE
  return (unsigned short)(r >> 16);
}

// ---------------- sigma (spectral norm) ----------------
__global__ void zero_t(float* __restrict__ t) { t[threadIdx.x] = 0.f; }

__global__ void wtu_acc(const float* __restrict__ W, const float* __restrict__ u,
                        float* __restrict__ t) {
  int tid = threadIdx.x;            // 256
  int j4 = tid * 4;
  int i0 = blockIdx.x * 16;
  f32x4 acc = {0.f, 0.f, 0.f, 0.f};
  for (int i = i0; i < i0 + 16; ++i) {
    float ui = u[i];
    f32x4 w4 = *(const f32x4*)(W + (size_t)i * INF + j4);
    acc[0] += w4[0] * ui; acc[1] += w4[1] * ui;
    acc[2] += w4[2] * ui; acc[3] += w4[3] * ui;
  }
  atomicAdd(&t[j4 + 0], acc[0]);
  atomicAdd(&t[j4 + 1], acc[1]);
  atomicAdd(&t[j4 + 2], acc[2]);
  atomicAdd(&t[j4 + 3], acc[3]);
}

__global__ void mv_w_t(const float* __restrict__ W, const float* __restrict__ t,
                       float* __restrict__ s) {
  int i = blockIdx.x;
  int tid = threadIdx.x;
  float p = 0.f;
  for (int j = tid; j < INF; j += 256) p += W[(size_t)i * INF + j] * t[j];
  __shared__ float red[256];
  red[tid] = p; __syncthreads();
  for (int k = 128; k > 0; k >>= 1) { if (tid < k) red[tid] += red[tid + k]; __syncthreads(); }
  if (tid == 0) s[i] = red[0];
}

__global__ void sigma_finish(const float* __restrict__ t, const float* __restrict__ s,
                             const float* __restrict__ st, const float* __restrict__ os,
                             float* __restrict__ scal) {
  __shared__ float r1[256], r2[256];
  int tid = threadIdx.x;
  float p1 = 0.f, p2 = 0.f;
  for (int i = tid; i < 1024; i += 256) { float a = t[i]; p1 += a * a; float b = s[i]; p2 += b * b; }
  r1[tid] = p1; r2[tid] = p2; __syncthreads();
  for (int k = 128; k > 0; k >>= 1) { if (tid < k) { r1[tid] += r1[tid + k]; r2[tid] += r2[tid + k]; } __syncthreads(); }
  if (tid == 0) {
    float nt = sqrtf(r1[0]);
    float ns = sqrtf(r2[0]);
    float nq = ns / (nt + 1e-12f);
    float sigma = nq * nq / (nq + 1e-12f);
    scal[0] = 1.f / sigma;
    scal[1] = log1pf(__expf(st[0]));
    scal[2] = os[0];
  }
}

// ---------------- weight casts into W' [1024][8192] ----------------
__global__ void wsn_cast(const float* __restrict__ w, const float* __restrict__ scal,
                         unsigned short* __restrict__ Wp) {
  float is = scal[0];
  int idx = blockIdx.x * 256 + threadIdx.x;
  int row = idx >> 7, i0 = (idx & 127) << 3;
  const f32x4* p = (const f32x4*)(w + (size_t)row * INF + i0);
  f32x4 a = p[0], b = p[1];
  u16x8 v;
  v[0] = f2bf(a[0] * is); v[1] = f2bf(a[1] * is); v[2] = f2bf(a[2] * is); v[3] = f2bf(a[3] * is);
  v[4] = f2bf(b[0] * is); v[5] = f2bf(b[1] * is); v[6] = f2bf(b[2] * is); v[7] = f2bf(b[3] * is);
  *(u16x8*)(Wp + (size_t)row * KTOT + KKAN + i0) = v;
}

__global__ void wkan_cast(const float* __restrict__ w, unsigned short* __restrict__ Wp) {
  __shared__ float row[KKAN];
  int orow = blockIdx.x;
  const float* src = w + (size_t)orow * KKAN;
  for (int c = threadIdx.x * 4; c < KKAN; c += 1024)
    *(f32x4*)&row[c] = *(const f32x4*)&src[c];
  __syncthreads();
  unsigned short* dst = Wp + (size_t)orow * KTOT;
  for (int r = threadIdx.x; r < 896; r += 256) {
    int g = r >> 7, i0 = (r & 127) << 3;
    u16x8 v;
#pragma unroll
    for (int j = 0; j < 8; j++) v[j] = f2bf(row[(i0 + j) * GG + g]);
    *(u16x8*)(dst + g * 1024 + i0) = v;
  }
}

// ---------------- activation expansion into A' [rows][8192] ----------------
__global__ void expand_kernel(const float* __restrict__ x,
                              const float* __restrict__ translation,
                              const float* __restrict__ scale,
                              unsigned short* __restrict__ Ap,
                              int row0, int nrows) {
  float tr[GG], iss[GG];
#pragma unroll
  for (int g = 0; g < GG; g++) {
    tr[g] = translation[g];
    float s = fabsf(scale[g]);
    iss[g] = 1.f / (s < 0.1f ? 0.1f : s);
  }
  int units = nrows * (INF / 8);
  int stride = gridDim.x * blockDim.x;
  for (int uu = blockIdx.x * blockDim.x + threadIdx.x; uu < units; uu += stride) {
    int nloc = uu >> 7;
    int i0 = (uu & 127) << 3;
    const f32x4* xp = (const f32x4*)(x + (size_t)(row0 + nloc) * INF + i0);
    f32x4 xa = xp[0], xb = xp[1];
    float xv[8] = {xa[0], xa[1], xa[2], xa[3], xb[0], xb[1], xb[2], xb[3]};
    u16x8 sb, kb[GG];
#pragma unroll
    for (int j = 0; j < 8; j++) {
      float xx = xv[j];
      float si = xx / (1.f + __expf(-xx));
      sb[j] = f2bf(si);
      float e2 = __expf(2.f * xx);
      float xn = 2.5f * (1.f - 2.f / (e2 + 1.f));
#pragma unroll
      for (int g = 0; g < GG; g++) {
        float xe = (xn - tr[g]) * iss[g];
        float t2 = xe * xe;
        float b = (1.f - t2) * __expf(-0.5f * t2);
        kb[g][j] = f2bf(b);
      }
    }
    unsigned short* rp = Ap + (size_t)nloc * KTOT;
    *(u16x8*)(rp + KKAN + i0) = sb;
#pragma unroll
    for (int g = 0; g < GG; g++) *(u16x8*)(rp + g * 1024 + i0) = kb[g];
  }
}

// ---------------- GEMM machinery ----------------
static __device__ __forceinline__ void gload16(const unsigned short* g, unsigned short* l) {
  __builtin_amdgcn_global_load_lds(
      (const __attribute__((address_space(1))) unsigned int*)g,
      (__attribute__((address_space(3))) unsigned int*)l, 16, 0, 0);
}

#define SCB   __builtin_amdgcn_sched_barrier(0)
#define SBAR  do { SCB; __builtin_amdgcn_s_barrier(); } while (0)
#define VM(N) asm volatile("s_waitcnt vmcnt(" #N ")" ::: "memory")
#define LG(N) asm volatile("s_waitcnt lgkmcnt(" #N ")" ::: "memory")

// stage full K-tile tt into buffer db: A 256x64 (4 gloads) + B 128x64 (2)
#define STAGE(db, tt) do { \
    const unsigned short* _sa = gA + (size_t)(tt) * 64; \
    const unsigned short* _sb = gB + (size_t)(tt) * 64; \
    unsigned short* _da = ldsS + (db) * 24576; \
    unsigned short* _db = ldsS + (db) * 24576 + 16384; \
    gload16(_sa,                       _da); \
    gload16(_sa + (size_t)64  * KTOT,  _da + 4096); \
    gload16(_sa + (size_t)128 * KTOT,  _da + 8192); \
    gload16(_sa + (size_t)192 * KTOT,  _da + 12288); \
    gload16(_sb,                       _db); \
    gload16(_sb + (size_t)64  * KTOT,  _db + 4096); \
  } while (0)

#define RD8(FA, FB, bb, kx) do { \
    _Pragma("unroll") for (int i = 0; i < 4; ++i) \
      FA[i] = *(const bf16x8*)(pA + (bb) * 49152 + i * 2048 + (kx)); \
    _Pragma("unroll") for (int j = 0; j < 4; ++j) \
      FB[j] = *(const bf16x8*)(pB + (bb) * 49152 + j * 2048 + (kx)); \
  } while (0)

#define MM16(FA, FB) do { _Pragma("unroll") for (int i = 0; i < 4; ++i) \
    _Pragma("unroll") for (int j = 0; j < 4; ++j) \
      acc[i][j] = __builtin_amdgcn_mfma_f32_16x16x32_bf16(FA[i], FB[j], acc[i][j], 0, 0, 0); } while (0)

// one K-tile, software-pipelined frags:
//  P1: read half2(t)->fY | stage(t+2) | MFMA(fX = half1(t)) | LG0 | W1 | SBAR
//  P2: read half1(t+1)->fX from buf nb | MFMA(fY) | LG0
#define TILE(tt, bb, nb, db, SS, NR, W1) do { \
    RD8(fYA, fYB, bb, kx1); \
    SCB; \
    if (SS) STAGE(db, (tt) + 2); \
    SCB; \
    __builtin_amdgcn_s_setprio(1); MM16(fXA, fXB); __builtin_amdgcn_s_setprio(0); \
    LG(0); SCB; \
    W1; \
    SBAR; \
    if (NR) { RD8(fXA, fXB, nb, kx0); SCB; } \
    __builtin_amdgcn_s_setprio(1); MM16(fYA, fYB); __builtin_amdgcn_s_setprio(0); \
    LG(0); SCB; \
  } while (0)

// BM=256 x BN=128, 8 waves (4M x 2N), K = 8192 merged, softthr at tile 112
__global__ __launch_bounds__(512, 2) void gemm_k(
    const unsigned short* __restrict__ A,   // [mt*256][8192] bf16
    const unsigned short* __restrict__ W,   // [1024][8192] bf16
    const float* __restrict__ bias,
    const float* __restrict__ scal,
    float* __restrict__ out) {              // [mt*256][1024]
  __shared__ unsigned short lds[73728];     // 3 buffers x 48 KB (A 32K | B 16K)

  int bid = blockIdx.x;
  int cpx = gridDim.x >> 3;                 // grid % 8 == 0 (mt*8)
  int swz = (bid & 7) * cpx + (bid >> 3);   // XCD-bijective; n-inner => A reuse
  int m0 = (swz >> 3) * 256;
  int n0 = (swz & 7) * 128;
  int tid = threadIdx.x;
  int wv = tid >> 6, l = tid & 63;
  int wr = wv >> 1, wc = wv & 1;            // 4M x 2N waves, 64x64 tiles

  float thr = scal[1], osc = scal[2];

  // staging: thread covers row (tid>>3) (+64/round), XOR-preswizzled 16B chunk
  int rowq = tid >> 3;
  int swk = ((tid & 7) ^ (rowq & 7)) << 3;
  const unsigned short* gA = A + (size_t)(m0 + rowq) * KTOT + swk;
  const unsigned short* gB = W + (size_t)(n0 + rowq) * KTOT + swk;
  unsigned short* ldsS = lds + wv * 512;    // wave-uniform dest base

  // frag reads (XOR on read side matches staging pre-swizzle)
  int lr = l & 15;
  int kb = (l >> 4) << 4;
  int xr = (l & 7) << 4;
  int kx0 = kb ^ xr;
  int kx1 = (64 | kb) ^ xr;
  const char* pA = (const char*)lds + (wr * 64 + lr) * 128;
  const char* pB = (const char*)lds + 32768 + (wc * 64 + lr) * 128;

  bf16x8 fXA[4], fXB[4], fYA[4], fYB[4];
  f32x4 acc[4][4] = {};

  // prologue: stage tiles 0,1 into buf 0,1; own t0 landed after VM(6);
  // barrier -> ALL waves' t0 landed; preload half1(t0) into fX.
  STAGE(0, 0);
  STAGE(1, 1);
  VM(6);
  SBAR;
  RD8(fXA, fXB, 0, kx0);
  LG(0); SCB;

  // kan segment: tiles 0..111
  for (int t = 0; t < 108; t += 3) {
    TILE(t,     0, 1, 2, 1, 1, VM(6));
    TILE(t + 1, 1, 2, 0, 1, 1, VM(6));
    TILE(t + 2, 2, 0, 1, 1, 1, VM(6));
  }
  TILE(108, 0, 1, 2, 1, 1, VM(6));
  TILE(109, 1, 2, 0, 1, 1, VM(6));
  TILE(110, 2, 0, 1, 1, 1, VM(6));
  TILE(111, 0, 1, 2, 1, 1, VM(6));

  // soft-threshold in-register at the kan/base boundary
#pragma unroll
  for (int i = 0; i < 4; ++i)
#pragma unroll
    for (int j = 0; j < 4; ++j)
#pragma unroll
      for (int e = 0; e < 4; ++e) {
        float v = acc[i][j][e];
        float a = fabsf(v) - thr;
        a = a > 0.f ? a : 0.f;
        acc[i][j][e] = v > 0.f ? a : -a;
      }

  // base segment: tiles 112..127
  for (int t = 112; t < 124; t += 3) {
    TILE(t,     1, 2, 0, 1, 1, VM(6));
    TILE(t + 1, 2, 0, 1, 1, 1, VM(6));
    TILE(t + 2, 0, 1, 2, 1, 1, VM(6));
  }
  TILE(124, 1, 2, 0, 1, 1, VM(6));
  TILE(125, 2, 0, 1, 1, 1, VM(6));   // stages tile 127 (last)
  TILE(126, 0, 1, 2, 0, 1, VM(0));   // no stage; drain so buf1(=t127) complete
  TILE(127, 1, 2, 0, 0, 0, (void)0); // no stage, no next-read

  // epilogue: out = (acc + bias) * oscale
  int rr = m0 + wr * 64 + ((l >> 4) << 2);
  int cc = n0 + wc * 64 + lr;
#pragma unroll
  for (int i = 0; i < 4; ++i)
#pragma unroll
    for (int j = 0; j < 4; ++j) {
      int c = cc + j * 16;
      float bc = bias[c];
#pragma unroll
      for (int e = 0; e < 4; ++e) {
        int r = rr + i * 16 + e;
        out[(size_t)r * OUTF + c] = (acc[i][j][e] + bc) * osc;
      }
    }
}

// ---------------------------------------------------------------------------
extern "C" void kernel_launch(void* const* d_in, const int* in_sizes, int n_in,
                              void* d_out, int out_size, void* d_ws, size_t ws_size,
                              hipStream_t stream) {
  const float* x              = (const float*)d_in[0];
  const float* base_w         = (const float*)d_in[1];
  const float* base_b         = (const float*)d_in[2];
  const float* u              = (const float*)d_in[3];
  const float* translation    = (const float*)d_in[4];
  const float* scale          = (const float*)d_in[5];
  const float* wavelet_w      = (const float*)d_in[6];
  const float* soft_threshold = (const float*)d_in[7];
  const float* output_scale   = (const float*)d_in[8];
  float* out = (float*)d_out;

  char* ws = (char*)d_ws;
  float* t_vec = (float*)ws;
  float* s_vec = t_vec + 1024;
  float* scal  = s_vec + 1024;
  unsigned short* Wp = (unsigned short*)(ws + 16384);    // 16 MB
  char* dynbuf = ws + 16384 + (size_t)KTOT * OUTF * 2;

  size_t fixed = 16384 + (size_t)KTOT * OUTF * 2;
  size_t avail = ws_size > fixed ? ws_size - fixed : 0;

  zero_t<<<1, 1024, 0, stream>>>(t_vec);
  wtu_acc<<<64, 256, 0, stream>>>(base_w, u, t_vec);
  mv_w_t<<<1024, 256, 0, stream>>>(base_w, t_vec, s_vec);
  sigma_finish<<<1, 256, 0, stream>>>(t_vec, s_vec, soft_threshold, output_scale, scal);
  wsn_cast<<<512, 256, 0, stream>>>(base_w, scal, Wp);
  wkan_cast<<<1024, 256, 0, stream>>>(wavelet_w, Wp);

  const size_t ROW = (size_t)KTOT * 2;      // A' bytes per row
  size_t total = (size_t)NROWS * ROW;
  int nch = (int)((total + (avail > 0 ? avail : 1) - 1) / (avail > 0 ? avail : 1));
  if (nch < 1) nch = 1;
  long mc = (((NROWS + nch - 1) / nch) + 255) & ~255L;
  while (mc > 256 && (size_t)mc * ROW > avail) mc -= 256;
  if (mc < 256) mc = 256;   // assume ws >= ~21 MB

  unsigned short* Ap = (unsigned short*)dynbuf;

  for (long r0 = 0; r0 < NROWS; r0 += mc) {
    long nr = (NROWS - r0 < mc) ? (NROWS - r0) : mc;
    expand_kernel<<<2048, 256, 0, stream>>>(x, translation, scale, Ap, (int)r0, (int)nr);
    int mt = (int)(nr / 256);
    gemm_k<<<mt * 8, 512, 0, stream>>>(Ap, Wp, base_b, scal, out + (size_t)r0 * OUTF);
  }
}